// Round 1
// baseline (428.909 us; speedup 1.0000x reference)
//
#include <hip/hip_runtime.h>

#define NN 8192
#define DDIM 128

// ---------------- Kernel 1: MLP (Linear->ReLU->Linear) + L2 normalize ----------------
// 128 threads = one output dim each; W1/W2 rows cached in VGPRs (amortized over rows).
__global__ __launch_bounds__(128, 1)
void mlp_norm_kernel(const float* __restrict__ X, const float* __restrict__ W1,
                     const float* __restrict__ b1, const float* __restrict__ W2,
                     const float* __restrict__ b2, float* __restrict__ emb,
                     int rowsPerBlock)
{
    const int t = threadIdx.x;
    float4 w1r[32], w2r[32];
#pragma unroll
    for (int i = 0; i < 32; ++i) w1r[i] = *(const float4*)&W1[t * DDIM + i * 4];
#pragma unroll
    for (int i = 0; i < 32; ++i) w2r[i] = *(const float4*)&W2[t * DDIM + i * 4];
    const float bb1 = b1[t], bb2 = b2[t];

    __shared__ float sx[DDIM];
    __shared__ float sh[DDIM];
    __shared__ float wred[2];

    const int row0 = blockIdx.x * rowsPerBlock;
    for (int r = 0; r < rowsPerBlock; ++r) {
        const int row = row0 + r;
        sx[t] = X[(size_t)row * DDIM + t];
        __syncthreads();
        float acc = bb1;
#pragma unroll
        for (int i = 0; i < 32; ++i) {
            const float4 xv = *(const float4*)&sx[i * 4];
            acc = fmaf(xv.x, w1r[i].x, acc);
            acc = fmaf(xv.y, w1r[i].y, acc);
            acc = fmaf(xv.z, w1r[i].z, acc);
            acc = fmaf(xv.w, w1r[i].w, acc);
        }
        sh[t] = fmaxf(acc, 0.f);
        __syncthreads();
        float acc2 = bb2;
#pragma unroll
        for (int i = 0; i < 32; ++i) {
            const float4 hv = *(const float4*)&sh[i * 4];
            acc2 = fmaf(hv.x, w2r[i].x, acc2);
            acc2 = fmaf(hv.y, w2r[i].y, acc2);
            acc2 = fmaf(hv.z, w2r[i].z, acc2);
            acc2 = fmaf(hv.w, w2r[i].w, acc2);
        }
        float sq = acc2 * acc2;
#pragma unroll
        for (int off = 1; off < 64; off <<= 1) sq += __shfl_xor(sq, off);
        if ((t & 63) == 0) wred[t >> 6] = sq;
        __syncthreads();
        const float ss = wred[0] + wred[1];
        const float inv = 1.0f / fmaxf(sqrtf(ss), 1e-12f);
        emb[(size_t)row * DDIM + t] = acc2 * inv;
        __syncthreads();   // protect sx/sh/wred for next iteration
    }
}

// ---------------- Kernel 2: sim = emb @ emb^T (f32, symmetric: upper tiles + mirror) ----
__global__ __launch_bounds__(256, 2)
void simgemm_kernel(const float* __restrict__ emb, float* __restrict__ out)
{
    __shared__ float sA[32][132];   // k-major, padded (stride 132 floats)
    __shared__ float sB[32][132];

    // decode triangular tile index: blockIdx.x -> (ti, tj), ti <= tj
    int rem = blockIdx.x;
    int ti = 0, w = 64;
    while (rem >= w) { rem -= w; ++ti; --w; }
    const int tj = ti + rem;
    const int m0 = ti * 128, n0 = tj * 128;

    const int tid = threadIdx.x;
    const int tx = tid & 15, ty = tid >> 4;
    const int lm = tid >> 1;            // row within tile, 0..127
    const int lk = (tid & 1) * 16;      // k-half base

    float acc[8][8];
#pragma unroll
    for (int i = 0; i < 8; ++i)
#pragma unroll
        for (int j = 0; j < 8; ++j) acc[i][j] = 0.f;

    for (int kc = 0; kc < DDIM; kc += 32) {
        __syncthreads();
#pragma unroll
        for (int j = 0; j < 4; ++j) {
            const int k4 = lk + j * 4;
            const float4 va = *(const float4*)&emb[(size_t)(m0 + lm) * DDIM + kc + k4];
            sA[k4 + 0][lm] = va.x; sA[k4 + 1][lm] = va.y;
            sA[k4 + 2][lm] = va.z; sA[k4 + 3][lm] = va.w;
            const float4 vb = *(const float4*)&emb[(size_t)(n0 + lm) * DDIM + kc + k4];
            sB[k4 + 0][lm] = vb.x; sB[k4 + 1][lm] = vb.y;
            sB[k4 + 2][lm] = vb.z; sB[k4 + 3][lm] = vb.w;
        }
        __syncthreads();
#pragma unroll
        for (int k = 0; k < 32; ++k) {
            const float4 a0 = *(const float4*)&sA[k][ty * 8];
            const float4 a1 = *(const float4*)&sA[k][ty * 8 + 4];
            const float4 b0 = *(const float4*)&sB[k][tx * 8];
            const float4 b1 = *(const float4*)&sB[k][tx * 8 + 4];
            const float a[8] = {a0.x, a0.y, a0.z, a0.w, a1.x, a1.y, a1.z, a1.w};
            const float b[8] = {b0.x, b0.y, b0.z, b0.w, b1.x, b1.y, b1.z, b1.w};
#pragma unroll
            for (int i = 0; i < 8; ++i)
#pragma unroll
                for (int j = 0; j < 8; ++j)
                    acc[i][j] = fmaf(a[i], b[j], acc[i][j]);
        }
    }

    // normal write: rows m0+ty*8+i, cols n0+tx*8..+7 (coalesced)
#pragma unroll
    for (int i = 0; i < 8; ++i) {
        const float4 lo = make_float4(acc[i][0], acc[i][1], acc[i][2], acc[i][3]);
        const float4 hi = make_float4(acc[i][4], acc[i][5], acc[i][6], acc[i][7]);
        float* p = &out[(size_t)(m0 + ty * 8 + i) * NN + n0 + tx * 8];
        *(float4*)p = lo;
        *(float4*)&p[4] = hi;
    }
    // mirror write (sim is symmetric): rows n0+tx*8+j, cols m0+ty*8..+7
    if (tj > ti) {
#pragma unroll
        for (int j = 0; j < 8; ++j) {
            const float4 lo = make_float4(acc[0][j], acc[1][j], acc[2][j], acc[3][j]);
            const float4 hi = make_float4(acc[4][j], acc[5][j], acc[6][j], acc[7][j]);
            float* p = &out[(size_t)(n0 + tx * 8 + j) * NN + m0 + ty * 8];
            *(float4*)p = lo;
            *(float4*)&p[4] = hi;
        }
    }
}

// ---------------- Kernel 3: per-row top-kp1 threshold + mask + ReLU (in place) --------
// Only positive values can survive ReLU, so rank positives only (uint bit-compare).
__global__ __launch_bounds__(256, 2)
void topk_relu_kernel(float* __restrict__ out, const int* __restrict__ kp1p)
{
    const int row = blockIdx.x;
    const int t = threadIdx.x;
    const int w = t >> 6;
    const unsigned kp1 = (unsigned)kp1p[0];

    __shared__ unsigned rowU[NN];
    __shared__ unsigned hist[4][256];
    __shared__ unsigned hist2[256];
    __shared__ unsigned segtot[4], segtot2[4];
    __shared__ unsigned sc[8];     // 0:bin1 1:above1 2:bin2 3:above2 4:tU 5:cands 6:found
    __shared__ unsigned cand[128];

    hist[0][t] = 0; hist[1][t] = 0; hist[2][t] = 0; hist[3][t] = 0; hist2[t] = 0;
    if (t < 8) sc[t] = 0;
    __syncthreads();

    float* rowp = out + (size_t)row * NN;

    // load row, stash raw bits, exponent histogram of positives (per-wave copies)
#pragma unroll
    for (int i = 0; i < 8; ++i) {
        const int idx = (i * 256 + t) * 4;
        const float4 v = *(const float4*)&rowp[idx];
        const unsigned u0 = __float_as_uint(v.x);
        const unsigned u1 = __float_as_uint(v.y);
        const unsigned u2 = __float_as_uint(v.z);
        const unsigned u3 = __float_as_uint(v.w);
        rowU[idx + 0] = u0; rowU[idx + 1] = u1;
        rowU[idx + 2] = u2; rowU[idx + 3] = u3;
        if (v.x > 0.f) atomicAdd(&hist[w][u0 >> 23], 1u);
        if (v.y > 0.f) atomicAdd(&hist[w][u1 >> 23], 1u);
        if (v.z > 0.f) atomicAdd(&hist[w][u2 >> 23], 1u);
        if (v.w > 0.f) atomicAdd(&hist[w][u3 >> 23], 1u);
    }
    __syncthreads();

    // level-1 suffix scan over 256 exponent bins
    const unsigned h1 = hist[0][t] + hist[1][t] + hist[2][t] + hist[3][t];
    unsigned v1 = h1;
#pragma unroll
    for (int off = 1; off < 64; off <<= 1) {
        const unsigned o = __shfl_down(v1, off);
        if ((t & 63) + off < 64) v1 += o;
    }
    if ((t & 63) == 0) segtot[w] = v1;
    __syncthreads();
    unsigned aseg = 0;
    for (int w2 = w + 1; w2 < 4; ++w2) aseg += segtot[w2];
    const unsigned above1 = aseg + (v1 - h1);
    if (above1 < kp1 && above1 + h1 >= kp1) { sc[0] = (unsigned)t; sc[1] = above1; sc[6] = 1u; }
    __syncthreads();

    unsigned tU = 1u;   // default: fewer than kp1 positives -> keep all positives
    if (sc[6]) {
        const unsigned bin1 = sc[0], ab1 = sc[1];
        // level-2: mantissa-top-8 histogram within boundary exponent bin
        for (int i = t; i < NN; i += 256) {
            const unsigned u = rowU[i];
            if (u && u < 0x80000000u && (u >> 23) == bin1)
                atomicAdd(&hist2[(u >> 15) & 0xFFu], 1u);
        }
        __syncthreads();
        const unsigned h2 = hist2[t];
        unsigned v2 = h2;
#pragma unroll
        for (int off = 1; off < 64; off <<= 1) {
            const unsigned o = __shfl_down(v2, off);
            if ((t & 63) + off < 64) v2 += o;
        }
        if ((t & 63) == 0) segtot2[w] = v2;
        __syncthreads();
        unsigned aseg2 = 0;
        for (int w2 = w + 1; w2 < 4; ++w2) aseg2 += segtot2[w2];
        const unsigned above2 = ab1 + aseg2 + (v2 - h2);
        if (above2 < kp1 && above2 + h2 >= kp1) { sc[2] = (unsigned)t; sc[3] = above2; }
        __syncthreads();

        // level-3: exact rank among candidates sharing the top-17 bits
        const unsigned prefix = (sc[0] << 8) | sc[2];
        const unsigned ab2 = sc[3];
        for (int i = t; i < NN; i += 256) {
            const unsigned u = rowU[i];
            if (u && u < 0x80000000u && (u >> 15) == prefix) {
                const unsigned p = atomicAdd(&sc[5], 1u);
                if (p < 128u) cand[p] = u;
            }
        }
        __syncthreads();
        const unsigned nc = sc[5] < 128u ? sc[5] : 128u;
        const unsigned rank_needed = kp1 - ab2;   // >= 1
        for (unsigned c = (unsigned)t; c < nc; c += 256u) {
            const unsigned cu = cand[c];
            unsigned g = 0, e = 0;
            for (unsigned j2 = 0; j2 < nc; ++j2) { g += (cand[j2] > cu); e += (cand[j2] == cu); }
            if (g < rank_needed && rank_needed <= g + e) atomicMax(&sc[4], cu);
        }
        __syncthreads();
        tU = sc[4] ? sc[4] : 1u;
    }
    __syncthreads();

    // rewrite row: keep positive values >= threshold, zero the rest (ReLU included)
#pragma unroll
    for (int i = 0; i < 8; ++i) {
        const int idx = (i * 256 + t) * 4;
        const unsigned u0 = rowU[idx + 0], u1 = rowU[idx + 1];
        const unsigned u2 = rowU[idx + 2], u3 = rowU[idx + 3];
        float4 o4;
        o4.x = (u0 < 0x80000000u && u0 >= tU) ? __uint_as_float(u0) : 0.f;
        o4.y = (u1 < 0x80000000u && u1 >= tU) ? __uint_as_float(u1) : 0.f;
        o4.z = (u2 < 0x80000000u && u2 >= tU) ? __uint_as_float(u2) : 0.f;
        o4.w = (u3 < 0x80000000u && u3 >= tU) ? __uint_as_float(u3) : 0.f;
        *(float4*)&rowp[idx] = o4;
    }
}

extern "C" void kernel_launch(void* const* d_in, const int* in_sizes, int n_in,
                              void* d_out, int out_size, void* d_ws, size_t ws_size,
                              hipStream_t stream)
{
    const float* X  = (const float*)d_in[0];
    const float* W1 = (const float*)d_in[1];
    const float* b1 = (const float*)d_in[2];
    const float* W2 = (const float*)d_in[3];
    const float* b2 = (const float*)d_in[4];
    const int* kp1  = (const int*)d_in[5];
    float* out = (float*)d_out;
    float* emb = (float*)d_ws;   // 8192*128*4 = 4 MB scratch

    mlp_norm_kernel<<<512, 128, 0, stream>>>(X, W1, b1, W2, b2, emb, 16);
    simgemm_kernel<<<2080, 256, 0, stream>>>(emb, out);
    topk_relu_kernel<<<NN, 256, 0, stream>>>(out, kp1);
}

// Round 2
// 329.685 us; speedup vs baseline: 1.3010x; 1.3010x over previous
//
#include <hip/hip_runtime.h>

#define NN 8192
#define DDIM 128

// ---------------- Kernel 1: MLP (Linear->ReLU->Linear) + L2 normalize ----------------
// 128 threads = one output dim each; W1/W2 rows cached in VGPRs (amortized over rows).
__global__ __launch_bounds__(128, 1)
void mlp_norm_kernel(const float* __restrict__ X, const float* __restrict__ W1,
                     const float* __restrict__ b1, const float* __restrict__ W2,
                     const float* __restrict__ b2, float* __restrict__ emb,
                     int rowsPerBlock)
{
    const int t = threadIdx.x;
    float4 w1r[32], w2r[32];
#pragma unroll
    for (int i = 0; i < 32; ++i) w1r[i] = *(const float4*)&W1[t * DDIM + i * 4];
#pragma unroll
    for (int i = 0; i < 32; ++i) w2r[i] = *(const float4*)&W2[t * DDIM + i * 4];
    const float bb1 = b1[t], bb2 = b2[t];

    __shared__ float sx[DDIM];
    __shared__ float sh[DDIM];
    __shared__ float wred[2];

    const int row0 = blockIdx.x * rowsPerBlock;
    for (int r = 0; r < rowsPerBlock; ++r) {
        const int row = row0 + r;
        sx[t] = X[(size_t)row * DDIM + t];
        __syncthreads();
        float acc = bb1;
#pragma unroll
        for (int i = 0; i < 32; ++i) {
            const float4 xv = *(const float4*)&sx[i * 4];
            acc = fmaf(xv.x, w1r[i].x, acc);
            acc = fmaf(xv.y, w1r[i].y, acc);
            acc = fmaf(xv.z, w1r[i].z, acc);
            acc = fmaf(xv.w, w1r[i].w, acc);
        }
        sh[t] = fmaxf(acc, 0.f);
        __syncthreads();
        float acc2 = bb2;
#pragma unroll
        for (int i = 0; i < 32; ++i) {
            const float4 hv = *(const float4*)&sh[i * 4];
            acc2 = fmaf(hv.x, w2r[i].x, acc2);
            acc2 = fmaf(hv.y, w2r[i].y, acc2);
            acc2 = fmaf(hv.z, w2r[i].z, acc2);
            acc2 = fmaf(hv.w, w2r[i].w, acc2);
        }
        float sq = acc2 * acc2;
#pragma unroll
        for (int off = 1; off < 64; off <<= 1) sq += __shfl_xor(sq, off);
        if ((t & 63) == 0) wred[t >> 6] = sq;
        __syncthreads();
        const float ss = wred[0] + wred[1];
        const float inv = 1.0f / fmaxf(sqrtf(ss), 1e-12f);
        emb[(size_t)row * DDIM + t] = acc2 * inv;
        __syncthreads();   // protect sx/sh/wred for next iteration
    }
}

// ---------------- Kernel 2: sim = emb @ emb^T (f32, symmetric: upper tiles + mirror) ----
__global__ __launch_bounds__(256, 2)
void simgemm_kernel(const float* __restrict__ emb, float* __restrict__ out)
{
    __shared__ float sA[32][132];   // k-major, padded (stride 132 floats)
    __shared__ float sB[32][132];

    // decode triangular tile index: blockIdx.x -> (ti, tj), ti <= tj
    int rem = blockIdx.x;
    int ti = 0, w = 64;
    while (rem >= w) { rem -= w; ++ti; --w; }
    const int tj = ti + rem;
    const int m0 = ti * 128, n0 = tj * 128;

    const int tid = threadIdx.x;
    const int tx = tid & 15, ty = tid >> 4;
    const int lm = tid >> 1;            // row within tile, 0..127
    const int lk = (tid & 1) * 16;      // k-half base

    float acc[8][8];
#pragma unroll
    for (int i = 0; i < 8; ++i)
#pragma unroll
        for (int j = 0; j < 8; ++j) acc[i][j] = 0.f;

    for (int kc = 0; kc < DDIM; kc += 32) {
        __syncthreads();
#pragma unroll
        for (int j = 0; j < 4; ++j) {
            const int k4 = lk + j * 4;
            const float4 va = *(const float4*)&emb[(size_t)(m0 + lm) * DDIM + kc + k4];
            sA[k4 + 0][lm] = va.x; sA[k4 + 1][lm] = va.y;
            sA[k4 + 2][lm] = va.z; sA[k4 + 3][lm] = va.w;
            const float4 vb = *(const float4*)&emb[(size_t)(n0 + lm) * DDIM + kc + k4];
            sB[k4 + 0][lm] = vb.x; sB[k4 + 1][lm] = vb.y;
            sB[k4 + 2][lm] = vb.z; sB[k4 + 3][lm] = vb.w;
        }
        __syncthreads();
#pragma unroll
        for (int k = 0; k < 32; ++k) {
            const float4 a0 = *(const float4*)&sA[k][ty * 8];
            const float4 a1 = *(const float4*)&sA[k][ty * 8 + 4];
            const float4 b0 = *(const float4*)&sB[k][tx * 8];
            const float4 b1 = *(const float4*)&sB[k][tx * 8 + 4];
            const float a[8] = {a0.x, a0.y, a0.z, a0.w, a1.x, a1.y, a1.z, a1.w};
            const float b[8] = {b0.x, b0.y, b0.z, b0.w, b1.x, b1.y, b1.z, b1.w};
#pragma unroll
            for (int i = 0; i < 8; ++i)
#pragma unroll
                for (int j = 0; j < 8; ++j)
                    acc[i][j] = fmaf(a[i], b[j], acc[i][j]);
        }
    }

    // normal write: rows m0+ty*8+i, cols n0+tx*8..+7 (coalesced)
#pragma unroll
    for (int i = 0; i < 8; ++i) {
        const float4 lo = make_float4(acc[i][0], acc[i][1], acc[i][2], acc[i][3]);
        const float4 hi = make_float4(acc[i][4], acc[i][5], acc[i][6], acc[i][7]);
        float* p = &out[(size_t)(m0 + ty * 8 + i) * NN + n0 + tx * 8];
        *(float4*)p = lo;
        *(float4*)&p[4] = hi;
    }
    // mirror write (sim is symmetric): rows n0+tx*8+j, cols m0+ty*8..+7
    if (tj > ti) {
#pragma unroll
        for (int j = 0; j < 8; ++j) {
            const float4 lo = make_float4(acc[0][j], acc[1][j], acc[2][j], acc[3][j]);
            const float4 hi = make_float4(acc[4][j], acc[5][j], acc[6][j], acc[7][j]);
            float* p = &out[(size_t)(n0 + tx * 8 + j) * NN + m0 + ty * 8];
            *(float4*)p = lo;
            *(float4*)&p[4] = hi;
        }
    }
}

// ---------------- Kernel 3: per-row top-kp1 threshold + mask + ReLU (in place) --------
// Register-resident bitwise radix-select: the row lives in VGPRs (32 per thread,
// positives as uint bits, non-positives as 0 -- post-ReLU only positives matter).
// Binary search MSB->LSB for the largest uint t with count(u >= t) >= kp1.
// No atomics, no row staging in LDS; one 4-word LDS exchange per bit (double-buffered).
__global__ __launch_bounds__(256)
void topk_relu_kernel(float* __restrict__ out, const int* __restrict__ kp1p)
{
    const int row = blockIdx.x;
    const int t = threadIdx.x;
    const int w = t >> 6;
    const unsigned kp1 = (unsigned)kp1p[0];
    float* rowp = out + (size_t)row * NN;

    // load row (coalesced: lane-contiguous float4), keep in registers
    unsigned u[32];
#pragma unroll
    for (int i = 0; i < 8; ++i) {
        const float4 v = *(const float4*)&rowp[(i * 256 + t) * 4];
        u[i * 4 + 0] = v.x > 0.f ? __float_as_uint(v.x) : 0u;
        u[i * 4 + 1] = v.y > 0.f ? __float_as_uint(v.y) : 0u;
        u[i * 4 + 2] = v.z > 0.f ? __float_as_uint(v.z) : 0u;
        u[i * 4 + 3] = v.w > 0.f ? __float_as_uint(v.w) : 0u;
    }

    __shared__ unsigned wsum[2][4];   // double-buffered per-wave partial counts

    unsigned thr = 0;
    for (int b = 30; b >= 0; --b) {
        const unsigned cand = thr | (1u << b);
        unsigned cnt = 0;
#pragma unroll
        for (int i = 0; i < 32; ++i) cnt += (u[i] >= cand) ? 1u : 0u;
        // wave butterfly reduce (64 lanes)
#pragma unroll
        for (int off = 1; off < 64; off <<= 1) cnt += __shfl_xor(cnt, off);
        const int p = b & 1;
        if ((t & 63) == 0) wsum[p][w] = cnt;
        __syncthreads();
        const unsigned tot = wsum[p][0] + wsum[p][1] + wsum[p][2] + wsum[p][3];
        if (tot >= kp1) thr = cand;   // uniform across block
    }
    // thr==0 => fewer than kp1 positives: keep all positives
    const unsigned teff = thr ? thr : 1u;

    // rewrite row: keep positives >= threshold, zero the rest (ReLU included)
#pragma unroll
    for (int i = 0; i < 8; ++i) {
        float4 o;
        o.x = (u[i * 4 + 0] >= teff) ? __uint_as_float(u[i * 4 + 0]) : 0.f;
        o.y = (u[i * 4 + 1] >= teff) ? __uint_as_float(u[i * 4 + 1]) : 0.f;
        o.z = (u[i * 4 + 2] >= teff) ? __uint_as_float(u[i * 4 + 2]) : 0.f;
        o.w = (u[i * 4 + 3] >= teff) ? __uint_as_float(u[i * 4 + 3]) : 0.f;
        *(float4*)&rowp[(i * 256 + t) * 4] = o;
    }
}

extern "C" void kernel_launch(void* const* d_in, const int* in_sizes, int n_in,
                              void* d_out, int out_size, void* d_ws, size_t ws_size,
                              hipStream_t stream)
{
    const float* X  = (const float*)d_in[0];
    const float* W1 = (const float*)d_in[1];
    const float* b1 = (const float*)d_in[2];
    const float* W2 = (const float*)d_in[3];
    const float* b2 = (const float*)d_in[4];
    const int* kp1  = (const int*)d_in[5];
    float* out = (float*)d_out;
    float* emb = (float*)d_ws;   // 8192*128*4 = 4 MB scratch

    mlp_norm_kernel<<<512, 128, 0, stream>>>(X, W1, b1, W2, b2, emb, 16);
    simgemm_kernel<<<2080, 256, 0, stream>>>(emb, out);
    topk_relu_kernel<<<NN, 256, 0, stream>>>(out, kp1);
}

// Round 3
// 329.185 us; speedup vs baseline: 1.3029x; 1.0015x over previous
//
#include <hip/hip_runtime.h>

#define NN 8192
#define DDIM 128

// ---------------- Kernel 1: MLP (Linear->ReLU->Linear) + L2 normalize ----------------
// 128 threads = one output dim each; W1/W2 rows cached in VGPRs (amortized over rows).
__global__ __launch_bounds__(128, 1)
void mlp_norm_kernel(const float* __restrict__ X, const float* __restrict__ W1,
                     const float* __restrict__ b1, const float* __restrict__ W2,
                     const float* __restrict__ b2, float* __restrict__ emb,
                     int rowsPerBlock)
{
    const int t = threadIdx.x;
    float4 w1r[32], w2r[32];
#pragma unroll
    for (int i = 0; i < 32; ++i) w1r[i] = *(const float4*)&W1[t * DDIM + i * 4];
#pragma unroll
    for (int i = 0; i < 32; ++i) w2r[i] = *(const float4*)&W2[t * DDIM + i * 4];
    const float bb1 = b1[t], bb2 = b2[t];

    __shared__ float sx[DDIM];
    __shared__ float sh[DDIM];
    __shared__ float wred[2];

    const int row0 = blockIdx.x * rowsPerBlock;
    for (int r = 0; r < rowsPerBlock; ++r) {
        const int row = row0 + r;
        sx[t] = X[(size_t)row * DDIM + t];
        __syncthreads();
        float acc = bb1;
#pragma unroll
        for (int i = 0; i < 32; ++i) {
            const float4 xv = *(const float4*)&sx[i * 4];
            acc = fmaf(xv.x, w1r[i].x, acc);
            acc = fmaf(xv.y, w1r[i].y, acc);
            acc = fmaf(xv.z, w1r[i].z, acc);
            acc = fmaf(xv.w, w1r[i].w, acc);
        }
        sh[t] = fmaxf(acc, 0.f);
        __syncthreads();
        float acc2 = bb2;
#pragma unroll
        for (int i = 0; i < 32; ++i) {
            const float4 hv = *(const float4*)&sh[i * 4];
            acc2 = fmaf(hv.x, w2r[i].x, acc2);
            acc2 = fmaf(hv.y, w2r[i].y, acc2);
            acc2 = fmaf(hv.z, w2r[i].z, acc2);
            acc2 = fmaf(hv.w, w2r[i].w, acc2);
        }
        float sq = acc2 * acc2;
#pragma unroll
        for (int off = 1; off < 64; off <<= 1) sq += __shfl_xor(sq, off);
        if ((t & 63) == 0) wred[t >> 6] = sq;
        __syncthreads();
        const float ss = wred[0] + wred[1];
        const float inv = 1.0f / fmaxf(sqrtf(ss), 1e-12f);
        emb[(size_t)row * DDIM + t] = acc2 * inv;
        __syncthreads();   // protect sx/sh/wred for next iteration
    }
}

// ---------------- Kernel 2: sim = emb @ emb^T (f32, symmetric: upper tiles + mirror) ----
__global__ __launch_bounds__(256, 2)
void simgemm_kernel(const float* __restrict__ emb, float* __restrict__ out)
{
    __shared__ float sA[32][132];   // k-major, padded (stride 132 floats)
    __shared__ float sB[32][132];

    // decode triangular tile index: blockIdx.x -> (ti, tj), ti <= tj
    int rem = blockIdx.x;
    int ti = 0, w = 64;
    while (rem >= w) { rem -= w; ++ti; --w; }
    const int tj = ti + rem;
    const int m0 = ti * 128, n0 = tj * 128;

    const int tid = threadIdx.x;
    const int tx = tid & 15, ty = tid >> 4;
    const int lm = tid >> 1;            // row within tile, 0..127
    const int lk = (tid & 1) * 16;      // k-half base

    float acc[8][8];
#pragma unroll
    for (int i = 0; i < 8; ++i)
#pragma unroll
        for (int j = 0; j < 8; ++j) acc[i][j] = 0.f;

    for (int kc = 0; kc < DDIM; kc += 32) {
        __syncthreads();
#pragma unroll
        for (int j = 0; j < 4; ++j) {
            const int k4 = lk + j * 4;
            const float4 va = *(const float4*)&emb[(size_t)(m0 + lm) * DDIM + kc + k4];
            sA[k4 + 0][lm] = va.x; sA[k4 + 1][lm] = va.y;
            sA[k4 + 2][lm] = va.z; sA[k4 + 3][lm] = va.w;
            const float4 vb = *(const float4*)&emb[(size_t)(n0 + lm) * DDIM + kc + k4];
            sB[k4 + 0][lm] = vb.x; sB[k4 + 1][lm] = vb.y;
            sB[k4 + 2][lm] = vb.z; sB[k4 + 3][lm] = vb.w;
        }
        __syncthreads();
#pragma unroll
        for (int k = 0; k < 32; ++k) {
            const float4 a0 = *(const float4*)&sA[k][ty * 8];
            const float4 a1 = *(const float4*)&sA[k][ty * 8 + 4];
            const float4 b0 = *(const float4*)&sB[k][tx * 8];
            const float4 b1 = *(const float4*)&sB[k][tx * 8 + 4];
            const float a[8] = {a0.x, a0.y, a0.z, a0.w, a1.x, a1.y, a1.z, a1.w};
            const float b[8] = {b0.x, b0.y, b0.z, b0.w, b1.x, b1.y, b1.z, b1.w};
#pragma unroll
            for (int i = 0; i < 8; ++i)
#pragma unroll
                for (int j = 0; j < 8; ++j)
                    acc[i][j] = fmaf(a[i], b[j], acc[i][j]);
        }
    }

    // normal write: rows m0+ty*8+i, cols n0+tx*8..+7 (coalesced)
#pragma unroll
    for (int i = 0; i < 8; ++i) {
        const float4 lo = make_float4(acc[i][0], acc[i][1], acc[i][2], acc[i][3]);
        const float4 hi = make_float4(acc[i][4], acc[i][5], acc[i][6], acc[i][7]);
        float* p = &out[(size_t)(m0 + ty * 8 + i) * NN + n0 + tx * 8];
        *(float4*)p = lo;
        *(float4*)&p[4] = hi;
    }
    // mirror write (sim is symmetric): rows n0+tx*8+j, cols m0+ty*8..+7
    if (tj > ti) {
#pragma unroll
        for (int j = 0; j < 8; ++j) {
            const float4 lo = make_float4(acc[0][j], acc[1][j], acc[2][j], acc[3][j]);
            const float4 hi = make_float4(acc[4][j], acc[5][j], acc[6][j], acc[7][j]);
            float* p = &out[(size_t)(n0 + tx * 8 + j) * NN + m0 + ty * 8];
            *(float4*)p = lo;
            *(float4*)&p[4] = hi;
        }
    }
}

// ---------------- Kernel 3: per-row top-kp1 threshold + mask + ReLU (in place) --------
// Register-resident bitwise radix-select: the row lives in VGPRs (32 per thread,
// positives as uint bits, non-positives as 0 -- post-ReLU only positives matter).
// Binary search MSB->LSB for the largest uint t with count(u >= t) >= kp1.
// No atomics, no row staging in LDS; one 4-word LDS exchange per bit (double-buffered).
__global__ __launch_bounds__(256)
void topk_relu_kernel(float* __restrict__ out, const int* __restrict__ kp1p)
{
    const int row = blockIdx.x;
    const int t = threadIdx.x;
    const int w = t >> 6;
    const unsigned kp1 = (unsigned)kp1p[0];
    float* rowp = out + (size_t)row * NN;

    // load row (coalesced: lane-contiguous float4), keep in registers
    unsigned u[32];
#pragma unroll
    for (int i = 0; i < 8; ++i) {
        const float4 v = *(const float4*)&rowp[(i * 256 + t) * 4];
        u[i * 4 + 0] = v.x > 0.f ? __float_as_uint(v.x) : 0u;
        u[i * 4 + 1] = v.y > 0.f ? __float_as_uint(v.y) : 0u;
        u[i * 4 + 2] = v.z > 0.f ? __float_as_uint(v.z) : 0u;
        u[i * 4 + 3] = v.w > 0.f ? __float_as_uint(v.w) : 0u;
    }

    __shared__ unsigned wsum[2][4];   // double-buffered per-wave partial counts

    unsigned thr = 0;
    for (int b = 30; b >= 0; --b) {
        const unsigned cand = thr | (1u << b);
        unsigned cnt = 0;
#pragma unroll
        for (int i = 0; i < 32; ++i) cnt += (u[i] >= cand) ? 1u : 0u;
        // wave butterfly reduce (64 lanes)
#pragma unroll
        for (int off = 1; off < 64; off <<= 1) cnt += __shfl_xor(cnt, off);
        const int p = b & 1;
        if ((t & 63) == 0) wsum[p][w] = cnt;
        __syncthreads();
        const unsigned tot = wsum[p][0] + wsum[p][1] + wsum[p][2] + wsum[p][3];
        if (tot >= kp1) thr = cand;   // uniform across block
    }
    // thr==0 => fewer than kp1 positives: keep all positives
    const unsigned teff = thr ? thr : 1u;

    // rewrite row: keep positives >= threshold, zero the rest (ReLU included)
#pragma unroll
    for (int i = 0; i < 8; ++i) {
        float4 o;
        o.x = (u[i * 4 + 0] >= teff) ? __uint_as_float(u[i * 4 + 0]) : 0.f;
        o.y = (u[i * 4 + 1] >= teff) ? __uint_as_float(u[i * 4 + 1]) : 0.f;
        o.z = (u[i * 4 + 2] >= teff) ? __uint_as_float(u[i * 4 + 2]) : 0.f;
        o.w = (u[i * 4 + 3] >= teff) ? __uint_as_float(u[i * 4 + 3]) : 0.f;
        *(float4*)&rowp[(i * 256 + t) * 4] = o;
    }
}

extern "C" void kernel_launch(void* const* d_in, const int* in_sizes, int n_in,
                              void* d_out, int out_size, void* d_ws, size_t ws_size,
                              hipStream_t stream)
{
    const float* X  = (const float*)d_in[0];
    const float* W1 = (const float*)d_in[1];
    const float* b1 = (const float*)d_in[2];
    const float* W2 = (const float*)d_in[3];
    const float* b2 = (const float*)d_in[4];
    const int* kp1  = (const int*)d_in[5];
    float* out = (float*)d_out;
    float* emb = (float*)d_ws;   // 8192*128*4 = 4 MB scratch

    mlp_norm_kernel<<<512, 128, 0, stream>>>(X, W1, b1, W2, b2, emb, 16);
    simgemm_kernel<<<2080, 256, 0, stream>>>(emb, out);
    topk_relu_kernel<<<NN, 256, 0, stream>>>(out, kp1);
}

// Round 5
// 277.009 us; speedup vs baseline: 1.5484x; 1.1884x over previous
//
#include <hip/hip_runtime.h>

#define NN 8192
#define DDIM 128

// ---------------- Kernel 1: MLP (Linear->ReLU->Linear) + L2 normalize ----------------
// FROZEN (bit-exact emb): any reordering perturbs sims at ~1e-7 and re-rolls the
// top-k selection-flip dice (gap at rank-31/32 ~ 9.6e-4, 8192 rows).
__global__ __launch_bounds__(128, 1)
void mlp_norm_kernel(const float* __restrict__ X, const float* __restrict__ W1,
                     const float* __restrict__ b1, const float* __restrict__ W2,
                     const float* __restrict__ b2, float* __restrict__ emb,
                     int rowsPerBlock)
{
    const int t = threadIdx.x;
    float4 w1r[32], w2r[32];
#pragma unroll
    for (int i = 0; i < 32; ++i) w1r[i] = *(const float4*)&W1[t * DDIM + i * 4];
#pragma unroll
    for (int i = 0; i < 32; ++i) w2r[i] = *(const float4*)&W2[t * DDIM + i * 4];
    const float bb1 = b1[t], bb2 = b2[t];

    __shared__ float sx[DDIM];
    __shared__ float sh[DDIM];
    __shared__ float wred[2];

    const int row0 = blockIdx.x * rowsPerBlock;
    for (int r = 0; r < rowsPerBlock; ++r) {
        const int row = row0 + r;
        sx[t] = X[(size_t)row * DDIM + t];
        __syncthreads();
        float acc = bb1;
#pragma unroll
        for (int i = 0; i < 32; ++i) {
            const float4 xv = *(const float4*)&sx[i * 4];
            acc = fmaf(xv.x, w1r[i].x, acc);
            acc = fmaf(xv.y, w1r[i].y, acc);
            acc = fmaf(xv.z, w1r[i].z, acc);
            acc = fmaf(xv.w, w1r[i].w, acc);
        }
        sh[t] = fmaxf(acc, 0.f);
        __syncthreads();
        float acc2 = bb2;
#pragma unroll
        for (int i = 0; i < 32; ++i) {
            const float4 hv = *(const float4*)&sh[i * 4];
            acc2 = fmaf(hv.x, w2r[i].x, acc2);
            acc2 = fmaf(hv.y, w2r[i].y, acc2);
            acc2 = fmaf(hv.z, w2r[i].z, acc2);
            acc2 = fmaf(hv.w, w2r[i].w, acc2);
        }
        float sq = acc2 * acc2;
#pragma unroll
        for (int off = 1; off < 64; off <<= 1) sq += __shfl_xor(sq, off);
        if ((t & 63) == 0) wred[t >> 6] = sq;
        __syncthreads();
        const float ss = wred[0] + wred[1];
        const float inv = 1.0f / fmaxf(sqrtf(ss), 1e-12f);
        emb[(size_t)row * DDIM + t] = acc2 * inv;
        __syncthreads();   // protect sx/sh/wred for next iteration
    }
}

// ---------------- Kernel 2: sim = emb @ emb^T (f32, symmetric: upper tiles + mirror) ----
// FROZEN (bit-exact sims): known zero-flip accumulation ordering vs the np reference.
__global__ __launch_bounds__(256, 2)
void simgemm_kernel(const float* __restrict__ emb, float* __restrict__ out)
{
    __shared__ float sA[32][132];   // k-major, padded (stride 132 floats)
    __shared__ float sB[32][132];

    // decode triangular tile index: blockIdx.x -> (ti, tj), ti <= tj
    int rem = blockIdx.x;
    int ti = 0, w = 64;
    while (rem >= w) { rem -= w; ++ti; --w; }
    const int tj = ti + rem;
    const int m0 = ti * 128, n0 = tj * 128;

    const int tid = threadIdx.x;
    const int tx = tid & 15, ty = tid >> 4;
    const int lm = tid >> 1;            // row within tile, 0..127
    const int lk = (tid & 1) * 16;      // k-half base

    float acc[8][8];
#pragma unroll
    for (int i = 0; i < 8; ++i)
#pragma unroll
        for (int j = 0; j < 8; ++j) acc[i][j] = 0.f;

    for (int kc = 0; kc < DDIM; kc += 32) {
        __syncthreads();
#pragma unroll
        for (int j = 0; j < 4; ++j) {
            const int k4 = lk + j * 4;
            const float4 va = *(const float4*)&emb[(size_t)(m0 + lm) * DDIM + kc + k4];
            sA[k4 + 0][lm] = va.x; sA[k4 + 1][lm] = va.y;
            sA[k4 + 2][lm] = va.z; sA[k4 + 3][lm] = va.w;
            const float4 vb = *(const float4*)&emb[(size_t)(n0 + lm) * DDIM + kc + k4];
            sB[k4 + 0][lm] = vb.x; sB[k4 + 1][lm] = vb.y;
            sB[k4 + 2][lm] = vb.z; sB[k4 + 3][lm] = vb.w;
        }
        __syncthreads();
#pragma unroll
        for (int k = 0; k < 32; ++k) {
            const float4 a0 = *(const float4*)&sA[k][ty * 8];
            const float4 a1 = *(const float4*)&sA[k][ty * 8 + 4];
            const float4 b0 = *(const float4*)&sB[k][tx * 8];
            const float4 b1 = *(const float4*)&sB[k][tx * 8 + 4];
            const float a[8] = {a0.x, a0.y, a0.z, a0.w, a1.x, a1.y, a1.z, a1.w};
            const float b[8] = {b0.x, b0.y, b0.z, b0.w, b1.x, b1.y, b1.z, b1.w};
#pragma unroll
            for (int i = 0; i < 8; ++i)
#pragma unroll
                for (int j = 0; j < 8; ++j)
                    acc[i][j] = fmaf(a[i], b[j], acc[i][j]);
        }
    }

    // normal write: rows m0+ty*8+i, cols n0+tx*8..+7 (coalesced)
#pragma unroll
    for (int i = 0; i < 8; ++i) {
        const float4 lo = make_float4(acc[i][0], acc[i][1], acc[i][2], acc[i][3]);
        const float4 hi = make_float4(acc[i][4], acc[i][5], acc[i][6], acc[i][7]);
        float* p = &out[(size_t)(m0 + ty * 8 + i) * NN + n0 + tx * 8];
        *(float4*)p = lo;
        *(float4*)&p[4] = hi;
    }
    // mirror write (sim is symmetric): rows n0+tx*8+j, cols m0+ty*8..+7
    if (tj > ti) {
#pragma unroll
        for (int j = 0; j < 8; ++j) {
            const float4 lo = make_float4(acc[0][j], acc[1][j], acc[2][j], acc[3][j]);
            const float4 hi = make_float4(acc[4][j], acc[5][j], acc[6][j], acc[7][j]);
            float* p = &out[(size_t)(n0 + tx * 8 + j) * NN + m0 + ty * 8];
            *(float4*)p = lo;
            *(float4*)&p[4] = hi;
        }
    }
}

// ---------------- Kernel 3: per-row top-kp1 threshold + mask + ReLU (in place) --------
// Register-resident bitwise radix-select; counting via ballot (v_cmp) + scalar popcount
// so the count loop costs 1 VALU op/element. Early exit: when count(>=prefix) == kp1
// exactly, threshold = min of that set (one reduce), skip remaining bits.
__global__ __launch_bounds__(256)
void topk_relu_kernel(float* __restrict__ out, const int* __restrict__ kp1p)
{
    const int row = blockIdx.x;
    const int t = threadIdx.x;
    const int w = t >> 6;
    const unsigned kp1 = (unsigned)kp1p[0];
    float* rowp = out + (size_t)row * NN;

    unsigned u[32];
#pragma unroll
    for (int i = 0; i < 8; ++i) {
        const float4 v = *(const float4*)&rowp[(i * 256 + t) * 4];
        u[i * 4 + 0] = v.x > 0.f ? __float_as_uint(v.x) : 0u;
        u[i * 4 + 1] = v.y > 0.f ? __float_as_uint(v.y) : 0u;
        u[i * 4 + 2] = v.z > 0.f ? __float_as_uint(v.z) : 0u;
        u[i * 4 + 3] = v.w > 0.f ? __float_as_uint(v.w) : 0u;
    }

    __shared__ unsigned wsum[2][4];
    __shared__ unsigned wmin[4];

    unsigned thr = 0;
    unsigned teff = 0;
    bool done = false;
    for (int b = 29; b >= 0 && !done; --b) {     // sims < 2.0 -> bits 31,30 are 0
        const unsigned cand = thr | (1u << b);
        unsigned cnt = 0;
#pragma unroll
        for (int i = 0; i < 32; ++i)
            cnt += (unsigned)__popcll(__ballot(u[i] >= cand));
        if ((t & 63) == 0) wsum[b & 1][w] = cnt;
        __syncthreads();
        const unsigned tot = wsum[b & 1][0] + wsum[b & 1][1] +
                             wsum[b & 1][2] + wsum[b & 1][3];
        if (tot >= kp1) {
            thr = cand;
            if (tot == kp1) {
                // exact: threshold = min{u : u >= cand}
                unsigned m = 0xFFFFFFFFu;
#pragma unroll
                for (int i = 0; i < 32; ++i)
                    if (u[i] >= cand && u[i] < m) m = u[i];
#pragma unroll
                for (int off = 1; off < 64; off <<= 1) {
                    const unsigned o = __shfl_xor(m, off);
                    if (o < m) m = o;
                }
                if ((t & 63) == 0) wmin[w] = m;
                __syncthreads();
                unsigned mm = wmin[0];
                if (wmin[1] < mm) mm = wmin[1];
                if (wmin[2] < mm) mm = wmin[2];
                if (wmin[3] < mm) mm = wmin[3];
                teff = mm;
                done = true;
            }
        }
    }
    if (teff == 0) teff = thr ? thr : 1u;   // thr==0: fewer than kp1 positives -> keep all

    // rewrite row: keep positives >= threshold, zero the rest (ReLU included)
#pragma unroll
    for (int i = 0; i < 8; ++i) {
        float4 o;
        o.x = (u[i * 4 + 0] >= teff) ? __uint_as_float(u[i * 4 + 0]) : 0.f;
        o.y = (u[i * 4 + 1] >= teff) ? __uint_as_float(u[i * 4 + 1]) : 0.f;
        o.z = (u[i * 4 + 2] >= teff) ? __uint_as_float(u[i * 4 + 2]) : 0.f;
        o.w = (u[i * 4 + 3] >= teff) ? __uint_as_float(u[i * 4 + 3]) : 0.f;
        *(float4*)&rowp[(i * 256 + t) * 4] = o;
    }
}

extern "C" void kernel_launch(void* const* d_in, const int* in_sizes, int n_in,
                              void* d_out, int out_size, void* d_ws, size_t ws_size,
                              hipStream_t stream)
{
    const float* X  = (const float*)d_in[0];
    const float* W1 = (const float*)d_in[1];
    const float* b1 = (const float*)d_in[2];
    const float* W2 = (const float*)d_in[3];
    const float* b2 = (const float*)d_in[4];
    const int* kp1  = (const int*)d_in[5];
    float* out = (float*)d_out;
    float* emb = (float*)d_ws;   // 8192*128*4 = 4 MB scratch

    mlp_norm_kernel<<<512, 128, 0, stream>>>(X, W1, b1, W2, b2, emb, 16);
    simgemm_kernel<<<2080, 256, 0, stream>>>(emb, out);
    topk_relu_kernel<<<NN, 256, 0, stream>>>(out, kp1);
}

// Round 6
// 272.804 us; speedup vs baseline: 1.5722x; 1.0154x over previous
//
#include <hip/hip_runtime.h>

#define NN 8192
#define DDIM 128

// ---------------- Kernel 1: MLP (Linear->ReLU->Linear) + L2 normalize ----------------
// FROZEN (bit-exact emb): any reordering perturbs sims at ~1e-7 and re-rolls the
// top-k selection-flip dice (gap at rank-31/32 ~ 9.6e-4, 8192 rows).
__global__ __launch_bounds__(128, 1)
void mlp_norm_kernel(const float* __restrict__ X, const float* __restrict__ W1,
                     const float* __restrict__ b1, const float* __restrict__ W2,
                     const float* __restrict__ b2, float* __restrict__ emb,
                     int rowsPerBlock)
{
    const int t = threadIdx.x;
    float4 w1r[32], w2r[32];
#pragma unroll
    for (int i = 0; i < 32; ++i) w1r[i] = *(const float4*)&W1[t * DDIM + i * 4];
#pragma unroll
    for (int i = 0; i < 32; ++i) w2r[i] = *(const float4*)&W2[t * DDIM + i * 4];
    const float bb1 = b1[t], bb2 = b2[t];

    __shared__ float sx[DDIM];
    __shared__ float sh[DDIM];
    __shared__ float wred[2];

    const int row0 = blockIdx.x * rowsPerBlock;
    for (int r = 0; r < rowsPerBlock; ++r) {
        const int row = row0 + r;
        sx[t] = X[(size_t)row * DDIM + t];
        __syncthreads();
        float acc = bb1;
#pragma unroll
        for (int i = 0; i < 32; ++i) {
            const float4 xv = *(const float4*)&sx[i * 4];
            acc = fmaf(xv.x, w1r[i].x, acc);
            acc = fmaf(xv.y, w1r[i].y, acc);
            acc = fmaf(xv.z, w1r[i].z, acc);
            acc = fmaf(xv.w, w1r[i].w, acc);
        }
        sh[t] = fmaxf(acc, 0.f);
        __syncthreads();
        float acc2 = bb2;
#pragma unroll
        for (int i = 0; i < 32; ++i) {
            const float4 hv = *(const float4*)&sh[i * 4];
            acc2 = fmaf(hv.x, w2r[i].x, acc2);
            acc2 = fmaf(hv.y, w2r[i].y, acc2);
            acc2 = fmaf(hv.z, w2r[i].z, acc2);
            acc2 = fmaf(hv.w, w2r[i].w, acc2);
        }
        float sq = acc2 * acc2;
#pragma unroll
        for (int off = 1; off < 64; off <<= 1) sq += __shfl_xor(sq, off);
        if ((t & 63) == 0) wred[t >> 6] = sq;
        __syncthreads();
        const float ss = wred[0] + wred[1];
        const float inv = 1.0f / fmaxf(sqrtf(ss), 1e-12f);
        emb[(size_t)row * DDIM + t] = acc2 * inv;
        __syncthreads();   // protect sx/sh/wred for next iteration
    }
}

// ---------------- Kernel 2: sim = emb @ emb^T (f32, symmetric: upper tiles + mirror) ----
// Numerics FROZEN: per-element fmaf chain over k=0..127 ascending (zero-flip ordering
// vs np reference). This round: occupancy 2 -> 4 waves/SIMD (__launch_bounds__(256,4));
// LDS 33.8 KB/block allows 4 blocks/CU (135 KB <= 160 KB); acc 8x8 = 64 VGPR fits the
// 128-VGPR/4-wave budget. More resident waves hide barrier drains + staging latency.
__global__ __launch_bounds__(256, 4)
void simgemm_kernel(const float* __restrict__ emb, float* __restrict__ out)
{
    __shared__ float sA[32][132];   // k-major, padded (stride 132 floats)
    __shared__ float sB[32][132];

    // decode triangular tile index: blockIdx.x -> (ti, tj), ti <= tj
    int rem = blockIdx.x;
    int ti = 0, w = 64;
    while (rem >= w) { rem -= w; ++ti; --w; }
    const int tj = ti + rem;
    const int m0 = ti * 128, n0 = tj * 128;

    const int tid = threadIdx.x;
    const int tx = tid & 15, ty = tid >> 4;
    const int lm = tid >> 1;            // row within tile, 0..127
    const int lk = (tid & 1) * 16;      // k-half base

    float acc[8][8];
#pragma unroll
    for (int i = 0; i < 8; ++i)
#pragma unroll
        for (int j = 0; j < 8; ++j) acc[i][j] = 0.f;

    for (int kc = 0; kc < DDIM; kc += 32) {
        __syncthreads();
#pragma unroll
        for (int j = 0; j < 4; ++j) {
            const int k4 = lk + j * 4;
            const float4 va = *(const float4*)&emb[(size_t)(m0 + lm) * DDIM + kc + k4];
            sA[k4 + 0][lm] = va.x; sA[k4 + 1][lm] = va.y;
            sA[k4 + 2][lm] = va.z; sA[k4 + 3][lm] = va.w;
            const float4 vb = *(const float4*)&emb[(size_t)(n0 + lm) * DDIM + kc + k4];
            sB[k4 + 0][lm] = vb.x; sB[k4 + 1][lm] = vb.y;
            sB[k4 + 2][lm] = vb.z; sB[k4 + 3][lm] = vb.w;
        }
        __syncthreads();
#pragma unroll
        for (int k = 0; k < 32; ++k) {
            const float4 a0 = *(const float4*)&sA[k][ty * 8];
            const float4 a1 = *(const float4*)&sA[k][ty * 8 + 4];
            const float4 b0 = *(const float4*)&sB[k][tx * 8];
            const float4 b1 = *(const float4*)&sB[k][tx * 8 + 4];
            const float a[8] = {a0.x, a0.y, a0.z, a0.w, a1.x, a1.y, a1.z, a1.w};
            const float b[8] = {b0.x, b0.y, b0.z, b0.w, b1.x, b1.y, b1.z, b1.w};
#pragma unroll
            for (int i = 0; i < 8; ++i)
#pragma unroll
                for (int j = 0; j < 8; ++j)
                    acc[i][j] = fmaf(a[i], b[j], acc[i][j]);
        }
    }

    // normal write: rows m0+ty*8+i, cols n0+tx*8..+7 (coalesced)
#pragma unroll
    for (int i = 0; i < 8; ++i) {
        const float4 lo = make_float4(acc[i][0], acc[i][1], acc[i][2], acc[i][3]);
        const float4 hi = make_float4(acc[i][4], acc[i][5], acc[i][6], acc[i][7]);
        float* p = &out[(size_t)(m0 + ty * 8 + i) * NN + n0 + tx * 8];
        *(float4*)p = lo;
        *(float4*)&p[4] = hi;
    }
    // mirror write (sim is symmetric): rows n0+tx*8+j, cols m0+ty*8..+7
    if (tj > ti) {
#pragma unroll
        for (int j = 0; j < 8; ++j) {
            const float4 lo = make_float4(acc[0][j], acc[1][j], acc[2][j], acc[3][j]);
            const float4 hi = make_float4(acc[4][j], acc[5][j], acc[6][j], acc[7][j]);
            float* p = &out[(size_t)(n0 + tx * 8 + j) * NN + m0 + ty * 8];
            *(float4*)p = lo;
            *(float4*)&p[4] = hi;
        }
    }
}

// ---------------- Kernel 3: per-row top-kp1 threshold + mask + ReLU (in place) --------
// Register-resident bitwise radix-select; counting via ballot (v_cmp) + scalar popcount
// so the count loop costs 1 VALU op/element. Early exit: when count(>=prefix) == kp1
// exactly, threshold = min of that set (one reduce), skip remaining bits.
__global__ __launch_bounds__(256)
void topk_relu_kernel(float* __restrict__ out, const int* __restrict__ kp1p)
{
    const int row = blockIdx.x;
    const int t = threadIdx.x;
    const int w = t >> 6;
    const unsigned kp1 = (unsigned)kp1p[0];
    float* rowp = out + (size_t)row * NN;

    unsigned u[32];
#pragma unroll
    for (int i = 0; i < 8; ++i) {
        const float4 v = *(const float4*)&rowp[(i * 256 + t) * 4];
        u[i * 4 + 0] = v.x > 0.f ? __float_as_uint(v.x) : 0u;
        u[i * 4 + 1] = v.y > 0.f ? __float_as_uint(v.y) : 0u;
        u[i * 4 + 2] = v.z > 0.f ? __float_as_uint(v.z) : 0u;
        u[i * 4 + 3] = v.w > 0.f ? __float_as_uint(v.w) : 0u;
    }

    __shared__ unsigned wsum[2][4];
    __shared__ unsigned wmin[4];

    unsigned thr = 0;
    unsigned teff = 0;
    bool done = false;
    for (int b = 29; b >= 0 && !done; --b) {     // sims < 2.0 -> bits 31,30 are 0
        const unsigned cand = thr | (1u << b);
        unsigned cnt = 0;
#pragma unroll
        for (int i = 0; i < 32; ++i)
            cnt += (unsigned)__popcll(__ballot(u[i] >= cand));
        if ((t & 63) == 0) wsum[b & 1][w] = cnt;
        __syncthreads();
        const unsigned tot = wsum[b & 1][0] + wsum[b & 1][1] +
                             wsum[b & 1][2] + wsum[b & 1][3];
        if (tot >= kp1) {
            thr = cand;
            if (tot == kp1) {
                // exact: threshold = min{u : u >= cand}
                unsigned m = 0xFFFFFFFFu;
#pragma unroll
                for (int i = 0; i < 32; ++i)
                    if (u[i] >= cand && u[i] < m) m = u[i];
#pragma unroll
                for (int off = 1; off < 64; off <<= 1) {
                    const unsigned o = __shfl_xor(m, off);
                    if (o < m) m = o;
                }
                if ((t & 63) == 0) wmin[w] = m;
                __syncthreads();
                unsigned mm = wmin[0];
                if (wmin[1] < mm) mm = wmin[1];
                if (wmin[2] < mm) mm = wmin[2];
                if (wmin[3] < mm) mm = wmin[3];
                teff = mm;
                done = true;
            }
        }
    }
    if (teff == 0) teff = thr ? thr : 1u;   // thr==0: fewer than kp1 positives -> keep all

    // rewrite row: keep positives >= threshold, zero the rest (ReLU included)
#pragma unroll
    for (int i = 0; i < 8; ++i) {
        float4 o;
        o.x = (u[i * 4 + 0] >= teff) ? __uint_as_float(u[i * 4 + 0]) : 0.f;
        o.y = (u[i * 4 + 1] >= teff) ? __uint_as_float(u[i * 4 + 1]) : 0.f;
        o.z = (u[i * 4 + 2] >= teff) ? __uint_as_float(u[i * 4 + 2]) : 0.f;
        o.w = (u[i * 4 + 3] >= teff) ? __uint_as_float(u[i * 4 + 3]) : 0.f;
        *(float4*)&rowp[(i * 256 + t) * 4] = o;
    }
}

extern "C" void kernel_launch(void* const* d_in, const int* in_sizes, int n_in,
                              void* d_out, int out_size, void* d_ws, size_t ws_size,
                              hipStream_t stream)
{
    const float* X  = (const float*)d_in[0];
    const float* W1 = (const float*)d_in[1];
    const float* b1 = (const float*)d_in[2];
    const float* W2 = (const float*)d_in[3];
    const float* b2 = (const float*)d_in[4];
    const int* kp1  = (const int*)d_in[5];
    float* out = (float*)d_out;
    float* emb = (float*)d_ws;   // 8192*128*4 = 4 MB scratch

    mlp_norm_kernel<<<512, 128, 0, stream>>>(X, W1, b1, W2, b2, emb, 16);
    simgemm_kernel<<<2080, 256, 0, stream>>>(emb, out);
    topk_relu_kernel<<<NN, 256, 0, stream>>>(out, kp1);
}